// Round 2
// baseline (77.221 us; speedup 1.0000x reference)
//
#include <hip/hip_runtime.h>

#define NTOK 4096
#define DMODEL 512
#define NHEAD 8
#define HDIM 64
#define KDIM 512

typedef __bf16 bf16x8 __attribute__((ext_vector_type(8)));
typedef float f32x4 __attribute__((ext_vector_type(4)));
typedef unsigned short u16x8 __attribute__((ext_vector_type(8)));
typedef unsigned short u16x4 __attribute__((ext_vector_type(4)));

#define NEGINF (-__builtin_inff())

__device__ __forceinline__ f32x4 mfma16(bf16x8 a, bf16x8 b, f32x4 c) {
  return __builtin_amdgcn_mfma_f32_16x16x32_bf16(a, b, c, 0, 0, 0);
}

__device__ __forceinline__ unsigned short f2bf(float f) {
  unsigned u = __builtin_bit_cast(unsigned, f);
  u += 0x7FFFu + ((u >> 16) & 1u);
  return (unsigned short)(u >> 16);
}

__device__ __forceinline__ void gload_lds16(const void* g, void* l) {
  __builtin_amdgcn_global_load_lds(
      (const __attribute__((address_space(1))) void*)g,
      (__attribute__((address_space(3))) void*)l, 16, 0, 0);
}

__device__ __forceinline__ int lbound(const int* __restrict__ b, int val) {
  int lo = 0, hi = NTOK;
  while (lo < hi) {
    int mid = (lo + hi) >> 1;
    if (b[mid] < val) lo = mid + 1; else hi = mid;
  }
  return lo;
}

// ---------------- convert: fp32 -> bf16 (scale folded into Wq/bq) ----------
__global__ void convert_kernel(const float* __restrict__ x,
                               const float* __restrict__ Wq, const float* __restrict__ bq,
                               const float* __restrict__ Wk, const float* __restrict__ bk,
                               const float* __restrict__ Wv, const float* __restrict__ bv,
                               const float* __restrict__ Wo,
                               unsigned short* __restrict__ xb,
                               unsigned short* __restrict__ wqkv,
                               unsigned short* __restrict__ wo,
                               float* __restrict__ bqkv) {
  const int XV = NTOK * DMODEL / 4;   // 524288
  const int WV = DMODEL * DMODEL / 4; // 65536
  const int total = XV + 4 * WV + 1536 / 4;
  for (int i = blockIdx.x * blockDim.x + threadIdx.x; i < total;
       i += gridDim.x * blockDim.x) {
    if (i < XV) {
      float4 v = ((const float4*)x)[i];
      unsigned short* d = xb + (size_t)i * 4;
      d[0] = f2bf(v.x); d[1] = f2bf(v.y); d[2] = f2bf(v.z); d[3] = f2bf(v.w);
    } else if (i < XV + 3 * WV) {
      int j = i - XV;
      const float* W; float sc; int jj;
      if (j < WV)          { W = Wq; sc = 0.125f; jj = j; }
      else if (j < 2 * WV) { W = Wk; sc = 1.0f;  jj = j - WV; }
      else                 { W = Wv; sc = 1.0f;  jj = j - 2 * WV; }
      float4 v = ((const float4*)W)[jj];
      unsigned short* d = wqkv + (size_t)j * 4;
      d[0] = f2bf(v.x * sc); d[1] = f2bf(v.y * sc);
      d[2] = f2bf(v.z * sc); d[3] = f2bf(v.w * sc);
    } else if (i < XV + 4 * WV) {
      int j = i - XV - 3 * WV;
      float4 v = ((const float4*)Wo)[j];
      unsigned short* d = wo + (size_t)j * 4;
      d[0] = f2bf(v.x); d[1] = f2bf(v.y); d[2] = f2bf(v.z); d[3] = f2bf(v.w);
    } else {
      int j = (i - XV - 4 * WV) * 4;
      #pragma unroll
      for (int t = 0; t < 4; ++t) {
        int e = j + t;
        float v = (e < 512) ? bq[e] * 0.125f
                 : (e < 1024 ? bk[e - 512] : bv[e - 1024]);
        bqkv[e] = v;
      }
    }
  }
}

// ---------------- GEMM: C = A(bf16) @ B^T(bf16) + bias -------------------
// MODE 0: A=xb[4096x512], B=wqkv[1536x512] -> writes qb/kb (scaled q) + vt (transposed)
// MODE 1: A=attn_out[4096x512], B=wo[512x512] -> writes fp32 d_out (+bo)
template <int MODE>
__global__ __launch_bounds__(256) void gemm_kernel(
    const unsigned short* __restrict__ A,
    const unsigned short* __restrict__ B,
    const float* __restrict__ biasv,
    float* __restrict__ outf,
    unsigned short* __restrict__ qb,
    unsigned short* __restrict__ kb,
    unsigned short* __restrict__ vt) {
  __shared__ __align__(16) unsigned short lds[2 * 128 * 64];
  unsigned short* ldsA = lds;
  unsigned short* ldsB = lds + 128 * 64;
  const int tid = threadIdx.x;
  const int lane = tid & 63;
  const int wv = tid >> 6;
  const int wm = wv >> 1, wn = wv & 1;
  const int r16 = lane & 15, g4 = lane >> 4;
  const int mt = blockIdx.x, nt = blockIdx.y;

  f32x4 acc[4][4];
  #pragma unroll
  for (int i = 0; i < 4; ++i)
    #pragma unroll
    for (int j = 0; j < 4; ++j)
      acc[i][j] = (f32x4){0.f, 0.f, 0.f, 0.f};

  const int srow = tid >> 3;          // 0..31
  const int scolb = (tid & 7) << 4;   // byte col 0..112

  for (int kt = 0; kt < KDIM / 64; ++kt) {
    __syncthreads();
    #pragma unroll
    for (int i = 0; i < 4; ++i) {
      int row = i * 32 + srow;
      int colu = scolb ^ ((row & 7) << 4);  // inverse-swizzled source (T2 via m173)
      const unsigned short* ga =
          A + (size_t)(mt * 128 + row) * KDIM + kt * 64 + (colu >> 1);
      gload_lds16(ga, (char*)ldsA + i * 4096 + wv * 1024);
      const unsigned short* gb =
          B + (size_t)(nt * 128 + row) * KDIM + kt * 64 + (colu >> 1);
      gload_lds16(gb, (char*)ldsB + i * 4096 + wv * 1024);
    }
    __syncthreads();
    #pragma unroll
    for (int ks = 0; ks < 2; ++ks) {
      bf16x8 af[4], bfr[4];
      #pragma unroll
      for (int f = 0; f < 4; ++f) {
        int ra = wm * 64 + f * 16 + r16;
        af[f] = *(const bf16x8*)((const char*)ldsA + ra * 128 +
                                 ((ks * 64 + g4 * 16) ^ ((ra & 7) << 4)));
        int rb = wn * 64 + f * 16 + r16;
        bfr[f] = *(const bf16x8*)((const char*)ldsB + rb * 128 +
                                  ((ks * 64 + g4 * 16) ^ ((rb & 7) << 4)));
      }
      #pragma unroll
      for (int fm = 0; fm < 4; ++fm)
        #pragma unroll
        for (int fn = 0; fn < 4; ++fn)
          acc[fm][fn] = mfma16(af[fm], bfr[fn], acc[fm][fn]);
    }
  }

  #pragma unroll
  for (int fm = 0; fm < 4; ++fm) {
    #pragma unroll
    for (int fn = 0; fn < 4; ++fn) {
      int mb = mt * 128 + wm * 64 + fm * 16 + g4 * 4;
      int n = nt * 128 + wn * 64 + fn * 16 + r16;
      float bv = biasv[n];
      if (MODE == 1) {
        #pragma unroll
        for (int r = 0; r < 4; ++r)
          outf[(size_t)(mb + r) * DMODEL + n] = acc[fm][fn][r] + bv;
      } else {
        if (n < 512) {
          #pragma unroll
          for (int r = 0; r < 4; ++r)
            qb[(size_t)(mb + r) * DMODEL + n] = f2bf(acc[fm][fn][r] + bv);
        } else if (n < 1024) {
          int nn = n - 512;
          #pragma unroll
          for (int r = 0; r < 4; ++r)
            kb[(size_t)(mb + r) * DMODEL + nn] = f2bf(acc[fm][fn][r] + bv);
        } else {
          int nn = n - 1024;  // nn = h*64 + d ; vt[nn][m]
          u16x4 pk;
          #pragma unroll
          for (int r = 0; r < 4; ++r) pk[r] = f2bf(acc[fm][fn][r] + bv);
          *(u16x4*)(vt + (size_t)nn * NTOK + mb) = pk;
        }
      }
    }
  }
}

// ---------------- flash attention with batch-block skipping ----------------
// grid 2048 = 256 q-tiles(16 rows) x 8 heads; 1 wave per block.
// blockIdx&7 = head -> per-head K/V L2 locality (XCD round-robin).
__global__ __launch_bounds__(64) void attn_kernel(
    const unsigned short* __restrict__ qb,
    const unsigned short* __restrict__ kb,
    const unsigned short* __restrict__ vt,
    const float* __restrict__ bias,
    const int* __restrict__ batch,
    unsigned short* __restrict__ ao) {
  __shared__ __align__(16) unsigned short pl[16 * 72];
  const int lane = threadIdx.x & 63;
  const int r16 = lane & 15, g4 = lane >> 4;
  const int h = blockIdx.x & 7;
  const int qrow0 = (blockIdx.x >> 3) * 16;

  const unsigned short* qrow = qb + (size_t)(qrow0 + r16) * DMODEL + h * HDIM + g4 * 8;
  bf16x8 qa0 = *(const bf16x8*)qrow;
  bf16x8 qa1 = *(const bf16x8*)(qrow + 32);

  int qbt[4];
  const float* bprow[4];
  const float* bh = bias + (size_t)h * NTOK * NTOK;
  #pragma unroll
  for (int r = 0; r < 4; ++r) {
    qbt[r] = batch[qrow0 + g4 * 4 + r];
    bprow[r] = bh + (size_t)(qrow0 + g4 * 4 + r) * NTOK;
  }

  // valid kv range for this 16-row tile (batch sorted)
  int blo = batch[qrow0];
  int bhi = batch[qrow0 + 15];
  int kvs = lbound(batch, blo);
  int kve = lbound(batch, bhi + 1);
  int tile0 = kvs >> 6, tile1 = (kve + 63) >> 6;

  float m_r[4] = {NEGINF, NEGINF, NEGINF, NEGINF};
  float l_r[4] = {0.f, 0.f, 0.f, 0.f};
  f32x4 o[4];
  #pragma unroll
  for (int d = 0; d < 4; ++d) o[d] = (f32x4){0.f, 0.f, 0.f, 0.f};

  for (int t = tile0; t < tile1; ++t) {
    int kvb = t << 6;
    // S = Q K^T (scale folded into q)
    f32x4 s[4];
    #pragma unroll
    for (int c = 0; c < 4; ++c) {
      const unsigned short* kp =
          kb + (size_t)(kvb + c * 16 + r16) * DMODEL + h * HDIM + g4 * 8;
      bf16x8 k0 = *(const bf16x8*)kp;
      bf16x8 k1 = *(const bf16x8*)(kp + 32);
      f32x4 z = (f32x4){0.f, 0.f, 0.f, 0.f};
      z = mfma16(qa0, k0, z);
      z = mfma16(qa1, k1, z);
      s[c] = z;
    }
    // bias + exact batch mask
    int kbt[4];
    #pragma unroll
    for (int c = 0; c < 4; ++c) kbt[c] = batch[kvb + c * 16 + r16];
    #pragma unroll
    for (int c = 0; c < 4; ++c) {
      #pragma unroll
      for (int r = 0; r < 4; ++r) {
        float bvv = bprow[r][kvb + c * 16 + r16];
        s[c][r] = (qbt[r] == kbt[c]) ? (s[c][r] + bvv) : NEGINF;
      }
    }
    // online softmax (row stats live in each 16-lane group)
    float scl[4];
    #pragma unroll
    for (int r = 0; r < 4; ++r) {
      float tm = fmaxf(fmaxf(s[0][r], s[1][r]), fmaxf(s[2][r], s[3][r]));
      tm = fmaxf(tm, __shfl_xor(tm, 1));
      tm = fmaxf(tm, __shfl_xor(tm, 2));
      tm = fmaxf(tm, __shfl_xor(tm, 4));
      tm = fmaxf(tm, __shfl_xor(tm, 8));
      float mn = fmaxf(m_r[r], tm);
      bool dead = (mn == NEGINF);   // nothing valid seen yet (pre-diagonal tiles)
      scl[r] = dead ? 1.0f : __expf(m_r[r] - mn);
      m_r[r] = mn;
      float rs = 0.f;
      #pragma unroll
      for (int c = 0; c < 4; ++c) {
        float p = dead ? 0.0f : __expf(s[c][r] - mn);
        s[c][r] = p;
        rs += p;
      }
      rs += __shfl_xor(rs, 1);
      rs += __shfl_xor(rs, 2);
      rs += __shfl_xor(rs, 4);
      rs += __shfl_xor(rs, 8);
      l_r[r] = l_r[r] * scl[r] + rs;
    }
    // P (C-layout) -> LDS -> A-fragment layout
    #pragma unroll
    for (int c = 0; c < 4; ++c)
      #pragma unroll
      for (int r = 0; r < 4; ++r)
        pl[(g4 * 4 + r) * 72 + c * 16 + r16] = f2bf(s[c][r]);
    asm volatile("" ::: "memory");
    u16x8 pr0 = *(const u16x8*)(pl + r16 * 72 + g4 * 8);
    u16x8 pr1 = *(const u16x8*)(pl + r16 * 72 + 32 + g4 * 8);
    bf16x8 pa0 = __builtin_bit_cast(bf16x8, pr0);
    bf16x8 pa1 = __builtin_bit_cast(bf16x8, pr1);
    // rescale O, then O += P V  (V read transposed: contiguous 16B)
    #pragma unroll
    for (int d = 0; d < 4; ++d) {
      #pragma unroll
      for (int r = 0; r < 4; ++r) o[d][r] *= scl[r];
    }
    #pragma unroll
    for (int d = 0; d < 4; ++d) {
      const unsigned short* vp =
          vt + (size_t)(h * HDIM + d * 16 + r16) * NTOK + kvb + g4 * 8;
      bf16x8 v0 = *(const bf16x8*)vp;
      bf16x8 v1 = *(const bf16x8*)(vp + 32);
      o[d] = mfma16(pa0, v0, o[d]);
      o[d] = mfma16(pa1, v1, o[d]);
    }
  }
  // normalize + store
  #pragma unroll
  for (int r = 0; r < 4; ++r) {
    float inv = (l_r[r] > 0.f) ? 1.0f / l_r[r] : 0.0f;
    #pragma unroll
    for (int d = 0; d < 4; ++d)
      ao[(size_t)(qrow0 + g4 * 4 + r) * DMODEL + h * HDIM + d * 16 + r16] =
          f2bf(o[d][r] * inv);
  }
}

// ---------------------------------------------------------------------------
extern "C" void kernel_launch(void* const* d_in, const int* in_sizes, int n_in,
                              void* d_out, int out_size, void* d_ws, size_t ws_size,
                              hipStream_t stream) {
  const float* x  = (const float*)d_in[0];
  const float* ab = (const float*)d_in[1];
  const int* batch = (const int*)d_in[2];
  const float* Wq = (const float*)d_in[3];
  const float* bq = (const float*)d_in[4];
  const float* Wk = (const float*)d_in[5];
  const float* bk = (const float*)d_in[6];
  const float* Wv = (const float*)d_in[7];
  const float* bv = (const float*)d_in[8];
  const float* Wo = (const float*)d_in[9];
  const float* bo = (const float*)d_in[10];
  float* out = (float*)d_out;

  char* ws = (char*)d_ws;
  const size_t MB = 1024 * 1024;
  unsigned short* xb   = (unsigned short*)(ws);            // 4 MB
  unsigned short* qb   = (unsigned short*)(ws + 4 * MB);   // 4 MB
  unsigned short* kb   = (unsigned short*)(ws + 8 * MB);   // 4 MB
  unsigned short* vt   = (unsigned short*)(ws + 12 * MB);  // 4 MB  [h*64+d][n]
  unsigned short* aout = (unsigned short*)(ws + 16 * MB);  // 4 MB
  unsigned short* wqkv = (unsigned short*)(ws + 20 * MB);  // 1.5 MB
  unsigned short* wo   = (unsigned short*)(ws + 22 * MB);  // 0.5 MB
  float* bqkv          = (float*)(ws + 23 * MB);           // 6 KB

  convert_kernel<<<dim3(1024), dim3(256), 0, stream>>>(
      x, Wq, bq, Wk, bk, Wv, bv, Wo, xb, wqkv, wo, bqkv);

  gemm_kernel<0><<<dim3(32, 12), dim3(256), 0, stream>>>(
      xb, wqkv, bqkv, nullptr, qb, kb, vt);

  attn_kernel<<<dim3(2048), dim3(64), 0, stream>>>(
      qb, kb, vt, ab, batch, aout);

  gemm_kernel<1><<<dim3(32, 4), dim3(256), 0, stream>>>(
      aout, wo, bo, out, nullptr, nullptr, nullptr);
}

// Round 3
// 54.731 us; speedup vs baseline: 1.4109x; 1.4109x over previous
//
#include <hip/hip_runtime.h>

#define NTOK 4096
#define DMODEL 512
#define NHEAD 8
#define HDIM 64
#define KDIM 512

typedef __bf16 bf16x8 __attribute__((ext_vector_type(8)));
typedef float f32x4 __attribute__((ext_vector_type(4)));
typedef unsigned short u16x8 __attribute__((ext_vector_type(8)));
typedef unsigned short u16x4 __attribute__((ext_vector_type(4)));

#define NEGINF (-__builtin_inff())

__device__ __forceinline__ f32x4 mfma16(bf16x8 a, bf16x8 b, f32x4 c) {
  return __builtin_amdgcn_mfma_f32_16x16x32_bf16(a, b, c, 0, 0, 0);
}

__device__ __forceinline__ unsigned short f2bf(float f) {
  unsigned u = __builtin_bit_cast(unsigned, f);
  u += 0x7FFFu + ((u >> 16) & 1u);
  return (unsigned short)(u >> 16);
}

__device__ __forceinline__ void gload_lds16(const void* g, void* l) {
  __builtin_amdgcn_global_load_lds(
      (const __attribute__((address_space(1))) void*)g,
      (__attribute__((address_space(3))) void*)l, 16, 0, 0);
}

__device__ __forceinline__ int lbound(const int* __restrict__ b, int val) {
  int lo = 0, hi = NTOK;
  while (lo < hi) {
    int mid = (lo + hi) >> 1;
    if (b[mid] < val) lo = mid + 1; else hi = mid;
  }
  return lo;
}

// ---------------- convert: fp32 -> bf16 (scale folded into Wq/bq) ----------
// Also precomputes per-q-tile valid kv-tile range table (batch sorted).
__global__ void convert_kernel(const float* __restrict__ x,
                               const float* __restrict__ Wq, const float* __restrict__ bq,
                               const float* __restrict__ Wk, const float* __restrict__ bk,
                               const float* __restrict__ Wv, const float* __restrict__ bv,
                               const float* __restrict__ Wo,
                               const int* __restrict__ batch,
                               unsigned short* __restrict__ xb,
                               unsigned short* __restrict__ wqkv,
                               unsigned short* __restrict__ wo,
                               float* __restrict__ bqkv,
                               int* __restrict__ qrange) {
  const int XV = NTOK * DMODEL / 4;   // 524288
  const int WV = DMODEL * DMODEL / 4; // 65536
  const int total = XV + 4 * WV + 1536 / 4;
  for (int i = blockIdx.x * blockDim.x + threadIdx.x; i < total;
       i += gridDim.x * blockDim.x) {
    if (i < XV) {
      float4 v = ((const float4*)x)[i];
      u16x4 pk = {f2bf(v.x), f2bf(v.y), f2bf(v.z), f2bf(v.w)};
      *(u16x4*)(xb + (size_t)i * 4) = pk;
    } else if (i < XV + 3 * WV) {
      int j = i - XV;
      const float* W; float sc; int jj;
      if (j < WV)          { W = Wq; sc = 0.125f; jj = j; }
      else if (j < 2 * WV) { W = Wk; sc = 1.0f;  jj = j - WV; }
      else                 { W = Wv; sc = 1.0f;  jj = j - 2 * WV; }
      float4 v = ((const float4*)W)[jj];
      u16x4 pk = {f2bf(v.x * sc), f2bf(v.y * sc), f2bf(v.z * sc), f2bf(v.w * sc)};
      *(u16x4*)(wqkv + (size_t)j * 4) = pk;
    } else if (i < XV + 4 * WV) {
      int j = i - XV - 3 * WV;
      float4 v = ((const float4*)Wo)[j];
      u16x4 pk = {f2bf(v.x), f2bf(v.y), f2bf(v.z), f2bf(v.w)};
      *(u16x4*)(wo + (size_t)j * 4) = pk;
    } else {
      int j = (i - XV - 4 * WV) * 4;
      #pragma unroll
      for (int t = 0; t < 4; ++t) {
        int e = j + t;
        float v = (e < 512) ? bq[e] * 0.125f
                 : (e < 1024 ? bk[e - 512] : bv[e - 1024]);
        bqkv[e] = v;
      }
    }
  }
  if (blockIdx.x == 0 && threadIdx.x < 256) {
    int q0 = threadIdx.x * 16;
    int blo = batch[q0];
    int bhi = batch[q0 + 15];
    qrange[threadIdx.x * 2]     = lbound(batch, blo) >> 6;
    qrange[threadIdx.x * 2 + 1] = (lbound(batch, bhi + 1) + 63) >> 6;
  }
}

// ---------------- GEMM: C = A(bf16) @ B^T(bf16) + bias -------------------
// BM=128, BN=64, BK=64. 4 waves in 2x2; wave tile 64x32 -> acc[4][2].
// MODE 0: A=xb[4096x512], B=wqkv[1536x512], grid(32,24) -> qb/kb + vt^T
// MODE 1: A=aout[4096x512], B=wo[512x512],  grid(32,8)  -> fp32 out (+bo)
template <int MODE>
__global__ __launch_bounds__(256) void gemm_kernel(
    const unsigned short* __restrict__ A,
    const unsigned short* __restrict__ B,
    const float* __restrict__ biasv,
    float* __restrict__ outf,
    unsigned short* __restrict__ qb,
    unsigned short* __restrict__ kb,
    unsigned short* __restrict__ vt) {
  __shared__ __align__(16) unsigned short lds[(128 + 64) * 64];
  unsigned short* ldsA = lds;
  unsigned short* ldsB = lds + 128 * 64;
  const int tid = threadIdx.x;
  const int lane = tid & 63;
  const int wv = tid >> 6;
  const int wm = wv >> 1, wn = wv & 1;
  const int r16 = lane & 15, g4 = lane >> 4;
  const int mt = blockIdx.x, nt = blockIdx.y;

  f32x4 acc[4][2];
  #pragma unroll
  for (int i = 0; i < 4; ++i)
    #pragma unroll
    for (int j = 0; j < 2; ++j)
      acc[i][j] = (f32x4){0.f, 0.f, 0.f, 0.f};

  const int srow = tid >> 3;          // 0..31
  const int scolb = (tid & 7) << 4;   // byte col 0..112

  for (int kt = 0; kt < KDIM / 64; ++kt) {
    __syncthreads();
    #pragma unroll
    for (int i = 0; i < 4; ++i) {
      int row = i * 32 + srow;
      int colu = scolb ^ ((row & 7) << 4);  // inverse-swizzled source
      const unsigned short* ga =
          A + (size_t)(mt * 128 + row) * KDIM + kt * 64 + (colu >> 1);
      gload_lds16(ga, (char*)ldsA + i * 4096 + wv * 1024);
    }
    #pragma unroll
    for (int i = 0; i < 2; ++i) {
      int row = i * 32 + srow;
      int colu = scolb ^ ((row & 7) << 4);
      const unsigned short* gb =
          B + (size_t)(nt * 64 + row) * KDIM + kt * 64 + (colu >> 1);
      gload_lds16(gb, (char*)ldsB + i * 4096 + wv * 1024);
    }
    __syncthreads();
    #pragma unroll
    for (int ks = 0; ks < 2; ++ks) {
      bf16x8 af[4], bfr[2];
      #pragma unroll
      for (int f = 0; f < 4; ++f) {
        int ra = wm * 64 + f * 16 + r16;
        af[f] = *(const bf16x8*)((const char*)ldsA + ra * 128 +
                                 ((ks * 64 + g4 * 16) ^ ((ra & 7) << 4)));
      }
      #pragma unroll
      for (int f = 0; f < 2; ++f) {
        int rb = wn * 32 + f * 16 + r16;
        bfr[f] = *(const bf16x8*)((const char*)ldsB + rb * 128 +
                                  ((ks * 64 + g4 * 16) ^ ((rb & 7) << 4)));
      }
      #pragma unroll
      for (int fm = 0; fm < 4; ++fm)
        #pragma unroll
        for (int fn = 0; fn < 2; ++fn)
          acc[fm][fn] = mfma16(af[fm], bfr[fn], acc[fm][fn]);
    }
  }

  #pragma unroll
  for (int fm = 0; fm < 4; ++fm) {
    #pragma unroll
    for (int fn = 0; fn < 2; ++fn) {
      int mb = mt * 128 + wm * 64 + fm * 16 + g4 * 4;
      int n = nt * 64 + wn * 32 + fn * 16 + r16;
      float bv = biasv[n];
      if (MODE == 1) {
        #pragma unroll
        for (int r = 0; r < 4; ++r)
          outf[(size_t)(mb + r) * DMODEL + n] = acc[fm][fn][r] + bv;
      } else {
        if (n < 512) {
          #pragma unroll
          for (int r = 0; r < 4; ++r)
            qb[(size_t)(mb + r) * DMODEL + n] = f2bf(acc[fm][fn][r] + bv);
        } else if (n < 1024) {
          int nn = n - 512;
          #pragma unroll
          for (int r = 0; r < 4; ++r)
            kb[(size_t)(mb + r) * DMODEL + nn] = f2bf(acc[fm][fn][r] + bv);
        } else {
          int nn = n - 1024;  // nn = h*64 + d ; vt[nn][m]
          u16x4 pk;
          #pragma unroll
          for (int r = 0; r < 4; ++r) pk[r] = f2bf(acc[fm][fn][r] + bv);
          *(u16x4*)(vt + (size_t)nn * NTOK + mb) = pk;
        }
      }
    }
  }
}

// ---------------- flash attention, batch-block skipping, T14 prefetch ------
// grid 2048 = 256 q-tiles(16 rows) x 8 heads; 1 wave per block.
// blockIdx&7 = head -> round-robin XCD assignment keeps per-head K/V in one L2.
__global__ __launch_bounds__(64) void attn_kernel(
    const unsigned short* __restrict__ qb,
    const unsigned short* __restrict__ kb,
    const unsigned short* __restrict__ vt,
    const float* __restrict__ bias,
    const int* __restrict__ batch,
    const int* __restrict__ qrange,
    unsigned short* __restrict__ ao) {
  __shared__ __align__(16) unsigned short pl[16 * 72];
  const int lane = threadIdx.x & 63;
  const int r16 = lane & 15, g4 = lane >> 4;
  const int h = blockIdx.x & 7;
  const int qt = blockIdx.x >> 3;
  const int qrow0 = qt * 16;
  const int hoff = h * HDIM;

  const unsigned short* qrow = qb + (size_t)(qrow0 + r16) * DMODEL + hoff + g4 * 8;
  bf16x8 qa0 = *(const bf16x8*)qrow;
  bf16x8 qa1 = *(const bf16x8*)(qrow + 32);

  int qbt[4];
  const float* bprow[4];
  const float* bh = bias + (size_t)h * NTOK * NTOK;
  #pragma unroll
  for (int r = 0; r < 4; ++r) {
    qbt[r] = batch[qrow0 + g4 * 4 + r];
    bprow[r] = bh + (size_t)(qrow0 + g4 * 4 + r) * NTOK;
  }

  const int tile0 = qrange[qt * 2];
  const int tile1 = qrange[qt * 2 + 1];

  float m_r[4] = {NEGINF, NEGINF, NEGINF, NEGINF};
  float l_r[4] = {0.f, 0.f, 0.f, 0.f};
  f32x4 o[4];
  #pragma unroll
  for (int d = 0; d < 4; ++d) o[d] = (f32x4){0.f, 0.f, 0.f, 0.f};

#define PREFETCH_KB(T, K0, K1, BV, KBT)                                      \
  {                                                                          \
    int kvb_ = (T) << 6;                                                     \
    _Pragma("unroll") for (int c = 0; c < 4; ++c) {                          \
      const unsigned short* kp =                                             \
          kb + (size_t)(kvb_ + c * 16 + r16) * DMODEL + hoff + g4 * 8;       \
      K0[c] = *(const bf16x8*)kp;                                            \
      K1[c] = *(const bf16x8*)(kp + 32);                                     \
    }                                                                        \
    _Pragma("unroll") for (int c = 0; c < 4; ++c) {                          \
      KBT[c] = batch[kvb_ + c * 16 + r16];                                   \
      _Pragma("unroll") for (int r = 0; r < 4; ++r)                          \
        BV[c][r] = bprow[r][kvb_ + c * 16 + r16];                            \
    }                                                                        \
  }

#define TILE_STEP(T, K0C, K1C, BVC, KBTC, K0N, K1N, BVN, KBTN)               \
  {                                                                          \
    int kvb = (T) << 6;                                                      \
    f32x4 s[4];                                                              \
    _Pragma("unroll") for (int c = 0; c < 4; ++c) {                          \
      f32x4 z = (f32x4){0.f, 0.f, 0.f, 0.f};                                 \
      z = mfma16(qa0, K0C[c], z);                                            \
      z = mfma16(qa1, K1C[c], z);                                            \
      s[c] = z;                                                              \
    }                                                                        \
    /* V loads for current tile (L2-resident: issued ~600cy before PV) */    \
    bf16x8 v0[4], v1[4];                                                     \
    _Pragma("unroll") for (int d = 0; d < 4; ++d) {                          \
      const unsigned short* vp =                                             \
          vt + (size_t)(hoff + d * 16 + r16) * NTOK + kvb + g4 * 8;          \
      v0[d] = *(const bf16x8*)vp;                                            \
      v1[d] = *(const bf16x8*)(vp + 32);                                     \
    }                                                                        \
    /* issue next tile's K + bias + tags (HBM latency hides under compute)*/ \
    {                                                                        \
      int tn_ = ((T) + 1 < tile1) ? (T) + 1 : (T);                           \
      PREFETCH_KB(tn_, K0N, K1N, BVN, KBTN);                                 \
    }                                                                        \
    _Pragma("unroll") for (int c = 0; c < 4; ++c)                            \
      _Pragma("unroll") for (int r = 0; r < 4; ++r)                          \
        s[c][r] = (qbt[r] == KBTC[c]) ? (s[c][r] + BVC[c][r]) : NEGINF;      \
    float scl[4];                                                            \
    _Pragma("unroll") for (int r = 0; r < 4; ++r) {                          \
      float tm = fmaxf(fmaxf(s[0][r], s[1][r]), fmaxf(s[2][r], s[3][r]));    \
      tm = fmaxf(tm, __shfl_xor(tm, 1));                                     \
      tm = fmaxf(tm, __shfl_xor(tm, 2));                                     \
      tm = fmaxf(tm, __shfl_xor(tm, 4));                                     \
      tm = fmaxf(tm, __shfl_xor(tm, 8));                                     \
      float mn = fmaxf(m_r[r], tm);                                          \
      bool dead = (mn == NEGINF);                                            \
      scl[r] = dead ? 1.0f : __expf(m_r[r] - mn);                            \
      m_r[r] = mn;                                                           \
      float rs = 0.f;                                                        \
      _Pragma("unroll") for (int c = 0; c < 4; ++c) {                        \
        float p = dead ? 0.0f : __expf(s[c][r] - mn);                        \
        s[c][r] = p;                                                         \
        rs += p;                                                             \
      }                                                                      \
      rs += __shfl_xor(rs, 1);                                               \
      rs += __shfl_xor(rs, 2);                                               \
      rs += __shfl_xor(rs, 4);                                               \
      rs += __shfl_xor(rs, 8);                                               \
      l_r[r] = l_r[r] * scl[r] + rs;                                         \
    }                                                                        \
    _Pragma("unroll") for (int c = 0; c < 4; ++c)                            \
      _Pragma("unroll") for (int r = 0; r < 4; ++r)                          \
        pl[(g4 * 4 + r) * 72 + c * 16 + r16] = f2bf(s[c][r]);                \
    asm volatile("" ::: "memory");                                           \
    u16x8 pr0 = *(const u16x8*)(pl + r16 * 72 + g4 * 8);                     \
    u16x8 pr1 = *(const u16x8*)(pl + r16 * 72 + 32 + g4 * 8);                \
    bf16x8 pa0 = __builtin_bit_cast(bf16x8, pr0);                            \
    bf16x8 pa1 = __builtin_bit_cast(bf16x8, pr1);                            \
    _Pragma("unroll") for (int d = 0; d < 4; ++d) {                          \
      _Pragma("unroll") for (int r = 0; r < 4; ++r) o[d][r] *= scl[r];       \
    }                                                                        \
    _Pragma("unroll") for (int d = 0; d < 4; ++d) {                          \
      o[d] = mfma16(pa0, v0[d], o[d]);                                       \
      o[d] = mfma16(pa1, v1[d], o[d]);                                       \
    }                                                                        \
  }

  // ping-pong prefetch register sets (no runtime-indexed arrays: rule #20)
  bf16x8 ka0[4], ka1[4], kc0[4], kc1[4];
  float bva[4][4], bvb[4][4];
  int kta[4], ktb[4];
  PREFETCH_KB(tile0, ka0, ka1, bva, kta);
  int t = tile0;
  while (true) {
    TILE_STEP(t, ka0, ka1, bva, kta, kc0, kc1, bvb, ktb);
    if (++t >= tile1) break;
    TILE_STEP(t, kc0, kc1, bvb, ktb, ka0, ka1, bva, kta);
    if (++t >= tile1) break;
  }

  // normalize + store
  #pragma unroll
  for (int r = 0; r < 4; ++r) {
    float inv = (l_r[r] > 0.f) ? 1.0f / l_r[r] : 0.0f;
    #pragma unroll
    for (int d = 0; d < 4; ++d)
      ao[(size_t)(qrow0 + g4 * 4 + r) * DMODEL + hoff + d * 16 + r16] =
          f2bf(o[d][r] * inv);
  }
#undef PREFETCH_KB
#undef TILE_STEP
}

// ---------------------------------------------------------------------------
extern "C" void kernel_launch(void* const* d_in, const int* in_sizes, int n_in,
                              void* d_out, int out_size, void* d_ws, size_t ws_size,
                              hipStream_t stream) {
  const float* x  = (const float*)d_in[0];
  const float* ab = (const float*)d_in[1];
  const int* batch = (const int*)d_in[2];
  const float* Wq = (const float*)d_in[3];
  const float* bq = (const float*)d_in[4];
  const float* Wk = (const float*)d_in[5];
  const float* bk = (const float*)d_in[6];
  const float* Wv = (const float*)d_in[7];
  const float* bv = (const float*)d_in[8];
  const float* Wo = (const float*)d_in[9];
  const float* bo = (const float*)d_in[10];
  float* out = (float*)d_out;

  char* ws = (char*)d_ws;
  const size_t MB = 1024 * 1024;
  unsigned short* xb   = (unsigned short*)(ws);            // 4 MB
  unsigned short* qb   = (unsigned short*)(ws + 4 * MB);   // 4 MB
  unsigned short* kb   = (unsigned short*)(ws + 8 * MB);   // 4 MB
  unsigned short* vt   = (unsigned short*)(ws + 12 * MB);  // 4 MB  [h*64+d][n]
  unsigned short* aout = (unsigned short*)(ws + 16 * MB);  // 4 MB
  unsigned short* wqkv = (unsigned short*)(ws + 20 * MB);  // 1.5 MB
  unsigned short* wo   = (unsigned short*)(ws + 22 * MB);  // 0.5 MB
  float* bqkv          = (float*)(ws + 23 * MB);           // 6 KB
  int* qrange          = (int*)(ws + 23 * MB + 65536);     // 2 KB

  convert_kernel<<<dim3(1024), dim3(256), 0, stream>>>(
      x, Wq, bq, Wk, bk, Wv, bv, Wo, batch, xb, wqkv, wo, bqkv, qrange);

  gemm_kernel<0><<<dim3(32, 24), dim3(256), 0, stream>>>(
      xb, wqkv, bqkv, nullptr, qb, kb, vt);

  attn_kernel<<<dim3(2048), dim3(64), 0, stream>>>(
      qb, kb, vt, ab, batch, qrange, aout);

  gemm_kernel<1><<<dim3(32, 8), dim3(256), 0, stream>>>(
      aout, wo, bo, out, nullptr, nullptr, nullptr);
}

// Round 4
// 54.111 us; speedup vs baseline: 1.4271x; 1.0115x over previous
//
#include <hip/hip_runtime.h>

#define NTOK 4096
#define DMODEL 512
#define NHEAD 8
#define HDIM 64
#define KDIM 512
#define KITER (KDIM / 64)

typedef __bf16 bf16x8 __attribute__((ext_vector_type(8)));
typedef float f32x4 __attribute__((ext_vector_type(4)));
typedef unsigned short u16x8 __attribute__((ext_vector_type(8)));
typedef unsigned short u16x4 __attribute__((ext_vector_type(4)));

#define NEGINF (-__builtin_inff())

__device__ __forceinline__ f32x4 mfma16(bf16x8 a, bf16x8 b, f32x4 c) {
  return __builtin_amdgcn_mfma_f32_16x16x32_bf16(a, b, c, 0, 0, 0);
}

__device__ __forceinline__ unsigned short f2bf(float f) {
  unsigned u = __builtin_bit_cast(unsigned, f);
  u += 0x7FFFu + ((u >> 16) & 1u);
  return (unsigned short)(u >> 16);
}

__device__ __forceinline__ void gload_lds16(const void* g, void* l) {
  __builtin_amdgcn_global_load_lds(
      (const __attribute__((address_space(1))) void*)g,
      (__attribute__((address_space(3))) void*)l, 16, 0, 0);
}

// ---------------- convert: fp32 -> bf16 (scale folded into Wq/bq) ----------
// Also precomputes per-q-tile valid kv-tile range table (batch sorted),
// binary-searching an LDS-staged copy of batch (no global pointer-chase).
__global__ void convert_kernel(const float* __restrict__ x,
                               const float* __restrict__ Wq, const float* __restrict__ bq,
                               const float* __restrict__ Wk, const float* __restrict__ bk,
                               const float* __restrict__ Wv, const float* __restrict__ bv,
                               const float* __restrict__ Wo,
                               const int* __restrict__ batch,
                               unsigned short* __restrict__ xb,
                               unsigned short* __restrict__ wqkv,
                               unsigned short* __restrict__ wo,
                               float* __restrict__ bqkv,
                               int* __restrict__ qrange) {
  __shared__ int bsh[NTOK];
  if (blockIdx.x == 0) {
    for (int i = threadIdx.x; i < NTOK; i += 256) bsh[i] = batch[i];
  }
  const int XV = NTOK * DMODEL / 4;   // 524288
  const int WV = DMODEL * DMODEL / 4; // 65536
  const int total = XV + 4 * WV + 1536 / 4;
  for (int i = blockIdx.x * blockDim.x + threadIdx.x; i < total;
       i += gridDim.x * blockDim.x) {
    if (i < XV) {
      float4 v = ((const float4*)x)[i];
      u16x4 pk = {f2bf(v.x), f2bf(v.y), f2bf(v.z), f2bf(v.w)};
      *(u16x4*)(xb + (size_t)i * 4) = pk;
    } else if (i < XV + 3 * WV) {
      int j = i - XV;
      const float* W; float sc; int jj;
      if (j < WV)          { W = Wq; sc = 0.125f; jj = j; }
      else if (j < 2 * WV) { W = Wk; sc = 1.0f;  jj = j - WV; }
      else                 { W = Wv; sc = 1.0f;  jj = j - 2 * WV; }
      float4 v = ((const float4*)W)[jj];
      u16x4 pk = {f2bf(v.x * sc), f2bf(v.y * sc), f2bf(v.z * sc), f2bf(v.w * sc)};
      *(u16x4*)(wqkv + (size_t)j * 4) = pk;
    } else if (i < XV + 4 * WV) {
      int j = i - XV - 3 * WV;
      float4 v = ((const float4*)Wo)[j];
      u16x4 pk = {f2bf(v.x), f2bf(v.y), f2bf(v.z), f2bf(v.w)};
      *(u16x4*)(wo + (size_t)j * 4) = pk;
    } else {
      int j = (i - XV - 4 * WV) * 4;
      #pragma unroll
      for (int t = 0; t < 4; ++t) {
        int e = j + t;
        float v = (e < 512) ? bq[e] * 0.125f
                 : (e < 1024 ? bk[e - 512] : bv[e - 1024]);
        bqkv[e] = v;
      }
    }
  }
  if (blockIdx.x == 0) {
    __syncthreads();
    if (threadIdx.x < 256) {
      int q0 = threadIdx.x * 16;
      int blo = bsh[q0];
      int bhi = bsh[q0 + 15];
      int lo = 0, hi = NTOK;
      while (lo < hi) { int m = (lo + hi) >> 1; if (bsh[m] < blo) lo = m + 1; else hi = m; }
      qrange[threadIdx.x * 2] = lo >> 6;
      lo = 0; hi = NTOK;
      while (lo < hi) { int m = (lo + hi) >> 1; if (bsh[m] < bhi + 1) lo = m + 1; else hi = m; }
      qrange[threadIdx.x * 2 + 1] = (lo + 63) >> 6;
    }
  }
}

// ---------------- GEMM: C = A(bf16) @ B^T(bf16) + bias -------------------
// BM=128, BN=64, BK=64. 4 waves in 2x2; wave tile 64x32 -> acc[4][2].
// 3-buffer 2-ahead pipeline with counted vmcnt (T3+T4): per iter
//   waitcnt vmcnt(6) -> s_barrier -> stage(t+2) -> ds_read+MFMA(t).
// MODE 0: A=xb[4096x512], B=wqkv[1536x512], grid(32,24) -> qb/kb + vt^T
// MODE 1: A=aout[4096x512], B=wo[512x512],  grid(32,8)  -> fp32 out (+bo)
#define BUFE (192 * 64)        // shorts per buffer (A 128x64 + B 64x64)
#define BUFB (BUFE * 2)        // bytes per buffer = 24576
template <int MODE>
__global__ __launch_bounds__(256) void gemm_kernel(
    const unsigned short* __restrict__ A,
    const unsigned short* __restrict__ B,
    const float* __restrict__ biasv,
    float* __restrict__ outf,
    unsigned short* __restrict__ qb,
    unsigned short* __restrict__ kb,
    unsigned short* __restrict__ vt) {
  __shared__ __align__(16) unsigned short lds[3 * BUFE];
  const int tid = threadIdx.x;
  const int lane = tid & 63;
  const int wv = tid >> 6;
  const int wm = wv >> 1, wn = wv & 1;
  const int r16 = lane & 15, g4 = lane >> 4;
  const int mt = blockIdx.x, nt = blockIdx.y;

  f32x4 acc[4][2];
  #pragma unroll
  for (int i = 0; i < 4; ++i)
    #pragma unroll
    for (int j = 0; j < 2; ++j)
      acc[i][j] = (f32x4){0.f, 0.f, 0.f, 0.f};

  const int srow = tid >> 3;          // 0..31
  const int scolb = (tid & 7) << 4;   // byte col 0..112

#define STAGE(KT, BI)                                                        \
  {                                                                          \
    char* bA = (char*)lds + (BI) * BUFB;                                     \
    char* bB = bA + 128 * 128;                                               \
    _Pragma("unroll") for (int i = 0; i < 4; ++i) {                          \
      int row = i * 32 + srow;                                               \
      int cu_ = scolb ^ ((row & 7) << 4);                                    \
      gload_lds16(A + (size_t)(mt * 128 + row) * KDIM + (KT) * 64 + (cu_ >> 1), \
                  bA + i * 4096 + wv * 1024);                                \
    }                                                                        \
    _Pragma("unroll") for (int i = 0; i < 2; ++i) {                          \
      int row = i * 32 + srow;                                               \
      int cu_ = scolb ^ ((row & 7) << 4);                                    \
      gload_lds16(B + (size_t)(nt * 64 + row) * KDIM + (KT) * 64 + (cu_ >> 1), \
                  bB + i * 4096 + wv * 1024);                                \
    }                                                                        \
  }

#define COMPUTE(BI)                                                          \
  {                                                                          \
    const char* base = (const char*)lds + (BI) * BUFB;                       \
    _Pragma("unroll") for (int ks = 0; ks < 2; ++ks) {                       \
      bf16x8 af[4], bfr[2];                                                  \
      _Pragma("unroll") for (int f = 0; f < 4; ++f) {                        \
        int ra = wm * 64 + f * 16 + r16;                                     \
        af[f] = *(const bf16x8*)(base + ra * 128 +                           \
                                 ((ks * 64 + g4 * 16) ^ ((ra & 7) << 4)));   \
      }                                                                      \
      _Pragma("unroll") for (int f = 0; f < 2; ++f) {                        \
        int rb = wn * 32 + f * 16 + r16;                                     \
        bfr[f] = *(const bf16x8*)(base + 128 * 128 + rb * 128 +              \
                                  ((ks * 64 + g4 * 16) ^ ((rb & 7) << 4)));  \
      }                                                                      \
      _Pragma("unroll") for (int fm = 0; fm < 4; ++fm)                       \
        _Pragma("unroll") for (int fn = 0; fn < 2; ++fn)                     \
          acc[fm][fn] = mfma16(af[fm], bfr[fn], acc[fm][fn]);                \
    }                                                                        \
  }

  STAGE(0, 0);
  STAGE(1, 1);
  int cur = 0;
  #pragma unroll
  for (int kt = 0; kt < KITER; ++kt) {
    if (kt < KITER - 1) {
      asm volatile("s_waitcnt vmcnt(6)" ::: "memory");
    } else {
      asm volatile("s_waitcnt vmcnt(0)" ::: "memory");
    }
    __builtin_amdgcn_s_barrier();
    if (kt + 2 < KITER) {
      int bi = cur ? cur - 1 : 2;  // (cur+2)%3
      STAGE(kt + 2, bi);
    }
    COMPUTE(cur);
    cur = (cur == 2) ? 0 : cur + 1;
  }
#undef STAGE
#undef COMPUTE

  #pragma unroll
  for (int fm = 0; fm < 4; ++fm) {
    #pragma unroll
    for (int fn = 0; fn < 2; ++fn) {
      int mb = mt * 128 + wm * 64 + fm * 16 + g4 * 4;
      int n = nt * 64 + wn * 32 + fn * 16 + r16;
      float bv = biasv[n];
      if (MODE == 1) {
        #pragma unroll
        for (int r = 0; r < 4; ++r)
          outf[(size_t)(mb + r) * DMODEL + n] = acc[fm][fn][r] + bv;
      } else {
        if (n < 512) {
          #pragma unroll
          for (int r = 0; r < 4; ++r)
            qb[(size_t)(mb + r) * DMODEL + n] = f2bf(acc[fm][fn][r] + bv);
        } else if (n < 1024) {
          int nn = n - 512;
          #pragma unroll
          for (int r = 0; r < 4; ++r)
            kb[(size_t)(mb + r) * DMODEL + nn] = f2bf(acc[fm][fn][r] + bv);
        } else {
          int nn = n - 1024;  // nn = h*64 + d ; vt[nn][m]
          u16x4 pk;
          #pragma unroll
          for (int r = 0; r < 4; ++r) pk[r] = f2bf(acc[fm][fn][r] + bv);
          *(u16x4*)(vt + (size_t)nn * NTOK + mb) = pk;
        }
      }
    }
  }
}

// ---------------- flash attention, batch-block skipping, T14 prefetch ------
// grid 2048 = 256 q-tiles(16 rows) x 8 heads; 1 wave per block.
// blockIdx&7 = head -> round-robin XCD assignment keeps per-head K/V in one L2.
__global__ __launch_bounds__(64) void attn_kernel(
    const unsigned short* __restrict__ qb,
    const unsigned short* __restrict__ kb,
    const unsigned short* __restrict__ vt,
    const float* __restrict__ bias,
    const int* __restrict__ batch,
    const int* __restrict__ qrange,
    unsigned short* __restrict__ ao) {
  __shared__ __align__(16) unsigned short pl[16 * 72];
  const int lane = threadIdx.x & 63;
  const int r16 = lane & 15, g4 = lane >> 4;
  const int h = blockIdx.x & 7;
  const int qt = blockIdx.x >> 3;
  const int qrow0 = qt * 16;
  const int hoff = h * HDIM;

  const unsigned short* qrow = qb + (size_t)(qrow0 + r16) * DMODEL + hoff + g4 * 8;
  bf16x8 qa0 = *(const bf16x8*)qrow;
  bf16x8 qa1 = *(const bf16x8*)(qrow + 32);

  int qbt[4];
  const float* bprow[4];
  const float* bh = bias + (size_t)h * NTOK * NTOK;
  #pragma unroll
  for (int r = 0; r < 4; ++r) {
    qbt[r] = batch[qrow0 + g4 * 4 + r];
    bprow[r] = bh + (size_t)(qrow0 + g4 * 4 + r) * NTOK;
  }

  const int tile0 = qrange[qt * 2];
  const int tile1 = qrange[qt * 2 + 1];

  float m_r[4] = {NEGINF, NEGINF, NEGINF, NEGINF};
  float l_r[4] = {0.f, 0.f, 0.f, 0.f};
  f32x4 o[4];
  #pragma unroll
  for (int d = 0; d < 4; ++d) o[d] = (f32x4){0.f, 0.f, 0.f, 0.f};

#define PREFETCH_KB(T, K0, K1, BV, KBT)                                      \
  {                                                                          \
    int kvb_ = (T) << 6;                                                     \
    _Pragma("unroll") for (int c = 0; c < 4; ++c) {                          \
      const unsigned short* kp =                                             \
          kb + (size_t)(kvb_ + c * 16 + r16) * DMODEL + hoff + g4 * 8;       \
      K0[c] = *(const bf16x8*)kp;                                            \
      K1[c] = *(const bf16x8*)(kp + 32);                                     \
    }                                                                        \
    _Pragma("unroll") for (int c = 0; c < 4; ++c) {                          \
      KBT[c] = batch[kvb_ + c * 16 + r16];                                   \
      _Pragma("unroll") for (int r = 0; r < 4; ++r)                          \
        BV[c][r] = bprow[r][kvb_ + c * 16 + r16];                            \
    }                                                                        \
  }

#define TILE_STEP(T, K0C, K1C, BVC, KBTC, K0N, K1N, BVN, KBTN)               \
  {                                                                          \
    int kvb = (T) << 6;                                                      \
    f32x4 s[4];                                                              \
    _Pragma("unroll") for (int c = 0; c < 4; ++c) {                          \
      f32x4 z = (f32x4){0.f, 0.f, 0.f, 0.f};                                 \
      z = mfma16(qa0, K0C[c], z);                                            \
      z = mfma16(qa1, K1C[c], z);                                            \
      s[c] = z;                                                              \
    }                                                                        \
    /* V loads for current tile (L2-resident: issued ~600cy before PV) */    \
    bf16x8 v0[4], v1[4];                                                     \
    _Pragma("unroll") for (int d = 0; d < 4; ++d) {                          \
      const unsigned short* vp =                                             \
          vt + (size_t)(hoff + d * 16 + r16) * NTOK + kvb + g4 * 8;          \
      v0[d] = *(const bf16x8*)vp;                                            \
      v1[d] = *(const bf16x8*)(vp + 32);                                     \
    }                                                                        \
    /* issue next tile's K + bias + tags (HBM latency hides under compute)*/ \
    {                                                                        \
      int tn_ = ((T) + 1 < tile1) ? (T) + 1 : (T);                           \
      PREFETCH_KB(tn_, K0N, K1N, BVN, KBTN);                                 \
    }                                                                        \
    _Pragma("unroll") for (int c = 0; c < 4; ++c)                            \
      _Pragma("unroll") for (int r = 0; r < 4; ++r)                          \
        s[c][r] = (qbt[r] == KBTC[c]) ? (s[c][r] + BVC[c][r]) : NEGINF;      \
    float scl[4];                                                            \
    _Pragma("unroll") for (int r = 0; r < 4; ++r) {                          \
      float tm = fmaxf(fmaxf(s[0][r], s[1][r]), fmaxf(s[2][r], s[3][r]));    \
      tm = fmaxf(tm, __shfl_xor(tm, 1));                                     \
      tm = fmaxf(tm, __shfl_xor(tm, 2));                                     \
      tm = fmaxf(tm, __shfl_xor(tm, 4));                                     \
      tm = fmaxf(tm, __shfl_xor(tm, 8));                                     \
      float mn = fmaxf(m_r[r], tm);                                          \
      bool dead = (mn == NEGINF);                                            \
      scl[r] = dead ? 1.0f : __expf(m_r[r] - mn);                            \
      m_r[r] = mn;                                                           \
      float rs = 0.f;                                                        \
      _Pragma("unroll") for (int c = 0; c < 4; ++c) {                        \
        float p = dead ? 0.0f : __expf(s[c][r] - mn);                        \
        s[c][r] = p;                                                         \
        rs += p;                                                             \
      }                                                                      \
      rs += __shfl_xor(rs, 1);                                               \
      rs += __shfl_xor(rs, 2);                                               \
      rs += __shfl_xor(rs, 4);                                               \
      rs += __shfl_xor(rs, 8);                                               \
      l_r[r] = l_r[r] * scl[r] + rs;                                         \
    }                                                                        \
    _Pragma("unroll") for (int c = 0; c < 4; ++c)                            \
      _Pragma("unroll") for (int r = 0; r < 4; ++r)                          \
        pl[(g4 * 4 + r) * 72 + c * 16 + r16] = f2bf(s[c][r]);                \
    asm volatile("" ::: "memory");                                           \
    u16x8 pr0 = *(const u16x8*)(pl + r16 * 72 + g4 * 8);                     \
    u16x8 pr1 = *(const u16x8*)(pl + r16 * 72 + 32 + g4 * 8);                \
    bf16x8 pa0 = __builtin_bit_cast(bf16x8, pr0);                            \
    bf16x8 pa1 = __builtin_bit_cast(bf16x8, pr1);                            \
    _Pragma("unroll") for (int d = 0; d < 4; ++d) {                          \
      _Pragma("unroll") for (int r = 0; r < 4; ++r) o[d][r] *= scl[r];       \
    }                                                                        \
    _Pragma("unroll") for (int d = 0; d < 4; ++d) {                          \
      o[d] = mfma16(pa0, v0[d], o[d]);                                       \
      o[d] = mfma16(pa1, v1[d], o[d]);                                       \
    }                                                                        \
  }

  // ping-pong prefetch register sets (no runtime-indexed arrays: rule #20)
  bf16x8 ka0[4], ka1[4], kc0[4], kc1[4];
  float bva[4][4], bvb[4][4];
  int kta[4], ktb[4];
  PREFETCH_KB(tile0, ka0, ka1, bva, kta);
  int t = tile0;
  while (true) {
    TILE_STEP(t, ka0, ka1, bva, kta, kc0, kc1, bvb, ktb);
    if (++t >= tile1) break;
    TILE_STEP(t, kc0, kc1, bvb, ktb, ka0, ka1, bva, kta);
    if (++t >= tile1) break;
  }

  // normalize + store
  #pragma unroll
  for (int r = 0; r < 4; ++r) {
    float inv = (l_r[r] > 0.f) ? 1.0f / l_r[r] : 0.0f;
    #pragma unroll
    for (int d = 0; d < 4; ++d)
      ao[(size_t)(qrow0 + g4 * 4 + r) * DMODEL + hoff + d * 16 + r16] =
          f2bf(o[d][r] * inv);
  }
#undef PREFETCH_KB
#undef TILE_STEP
}

// ---------------------------------------------------------------------------
extern "C" void kernel_launch(void* const* d_in, const int* in_sizes, int n_in,
                              void* d_out, int out_size, void* d_ws, size_t ws_size,
                              hipStream_t stream) {
  const float* x  = (const float*)d_in[0];
  const float* ab = (const float*)d_in[1];
  const int* batch = (const int*)d_in[2];
  const float* Wq = (const float*)d_in[3];
  const float* bq = (const float*)d_in[4];
  const float* Wk = (const float*)d_in[5];
  const float* bk = (const float*)d_in[6];
  const float* Wv = (const float*)d_in[7];
  const float* bv = (const float*)d_in[8];
  const float* Wo = (const float*)d_in[9];
  const float* bo = (const float*)d_in[10];
  float* out = (float*)d_out;

  char* ws = (char*)d_ws;
  const size_t MB = 1024 * 1024;
  unsigned short* xb   = (unsigned short*)(ws);            // 4 MB
  unsigned short* qb   = (unsigned short*)(ws + 4 * MB);   // 4 MB
  unsigned short* kb   = (unsigned short*)(ws + 8 * MB);   // 4 MB
  unsigned short* vt   = (unsigned short*)(ws + 12 * MB);  // 4 MB  [h*64+d][n]
  unsigned short* aout = (unsigned short*)(ws + 16 * MB);  // 4 MB
  unsigned short* wqkv = (unsigned short*)(ws + 20 * MB);  // 1.5 MB
  unsigned short* wo   = (unsigned short*)(ws + 22 * MB);  // 0.5 MB
  float* bqkv          = (float*)(ws + 23 * MB);           // 6 KB
  int* qrange          = (int*)(ws + 23 * MB + 65536);     // 2 KB

  convert_kernel<<<dim3(1024), dim3(256), 0, stream>>>(
      x, Wq, bq, Wk, bk, Wv, bv, Wo, batch, xb, wqkv, wo, bqkv, qrange);

  gemm_kernel<0><<<dim3(32, 24), dim3(256), 0, stream>>>(
      xb, wqkv, bqkv, nullptr, qb, kb, vt);

  attn_kernel<<<dim3(2048), dim3(64), 0, stream>>>(
      qb, kb, vt, ab, batch, qrange, aout);

  gemm_kernel<1><<<dim3(32, 8), dim3(256), 0, stream>>>(
      aout, wo, bo, out, nullptr, nullptr, nullptr);
}

// Round 5
// 51.648 us; speedup vs baseline: 1.4951x; 1.0477x over previous
//
#include <hip/hip_runtime.h>

#define NTOK 4096
#define DMODEL 512
#define NHEAD 8
#define HDIM 64
#define KDIM 512
#define KITER (KDIM / 64)

typedef __bf16 bf16x8 __attribute__((ext_vector_type(8)));
typedef float f32x4 __attribute__((ext_vector_type(4)));
typedef unsigned short u16x8 __attribute__((ext_vector_type(8)));
typedef unsigned short u16x4 __attribute__((ext_vector_type(4)));

#define NEGINF (-__builtin_inff())

__device__ __forceinline__ f32x4 mfma16(bf16x8 a, bf16x8 b, f32x4 c) {
  return __builtin_amdgcn_mfma_f32_16x16x32_bf16(a, b, c, 0, 0, 0);
}

__device__ __forceinline__ unsigned short f2bf(float f) {
  unsigned u = __builtin_bit_cast(unsigned, f);
  u += 0x7FFFu + ((u >> 16) & 1u);
  return (unsigned short)(u >> 16);
}

__device__ __forceinline__ void gload_lds16(const void* g, void* l) {
  __builtin_amdgcn_global_load_lds(
      (const __attribute__((address_space(1))) void*)g,
      (__attribute__((address_space(3))) void*)l, 16, 0, 0);
}

// ---------------- convert: fp32 -> bf16 (scale folded into Wq/bq) ----------
// Also precomputes per-q-tile valid kv-tile range table (batch sorted),
// binary-searching an LDS-staged copy of batch (no global pointer-chase).
__global__ void convert_kernel(const float* __restrict__ x,
                               const float* __restrict__ Wq, const float* __restrict__ bq,
                               const float* __restrict__ Wk, const float* __restrict__ bk,
                               const float* __restrict__ Wv, const float* __restrict__ bv,
                               const float* __restrict__ Wo,
                               const int* __restrict__ batch,
                               unsigned short* __restrict__ xb,
                               unsigned short* __restrict__ wqkv,
                               unsigned short* __restrict__ wo,
                               float* __restrict__ bqkv,
                               int* __restrict__ qrange) {
  __shared__ int bsh[NTOK];
  if (blockIdx.x == 0) {
    for (int i = threadIdx.x; i < NTOK; i += 256) bsh[i] = batch[i];
  }
  const int XV = NTOK * DMODEL / 4;   // 524288
  const int WV = DMODEL * DMODEL / 4; // 65536
  const int total = XV + 4 * WV + 1536 / 4;
  for (int i = blockIdx.x * blockDim.x + threadIdx.x; i < total;
       i += gridDim.x * blockDim.x) {
    if (i < XV) {
      float4 v = ((const float4*)x)[i];
      u16x4 pk = {f2bf(v.x), f2bf(v.y), f2bf(v.z), f2bf(v.w)};
      *(u16x4*)(xb + (size_t)i * 4) = pk;
    } else if (i < XV + 3 * WV) {
      int j = i - XV;
      const float* W; float sc; int jj;
      if (j < WV)          { W = Wq; sc = 0.125f; jj = j; }
      else if (j < 2 * WV) { W = Wk; sc = 1.0f;  jj = j - WV; }
      else                 { W = Wv; sc = 1.0f;  jj = j - 2 * WV; }
      float4 v = ((const float4*)W)[jj];
      u16x4 pk = {f2bf(v.x * sc), f2bf(v.y * sc), f2bf(v.z * sc), f2bf(v.w * sc)};
      *(u16x4*)(wqkv + (size_t)j * 4) = pk;
    } else if (i < XV + 4 * WV) {
      int j = i - XV - 3 * WV;
      float4 v = ((const float4*)Wo)[j];
      u16x4 pk = {f2bf(v.x), f2bf(v.y), f2bf(v.z), f2bf(v.w)};
      *(u16x4*)(wo + (size_t)j * 4) = pk;
    } else {
      int j = (i - XV - 4 * WV) * 4;
      #pragma unroll
      for (int t = 0; t < 4; ++t) {
        int e = j + t;
        float v = (e < 512) ? bq[e] * 0.125f
                 : (e < 1024 ? bk[e - 512] : bv[e - 1024]);
        bqkv[e] = v;
      }
    }
  }
  if (blockIdx.x == 0) {
    __syncthreads();
    if (threadIdx.x < 256) {
      int q0 = threadIdx.x * 16;
      int blo = bsh[q0];
      int bhi = bsh[q0 + 15];
      int lo = 0, hi = NTOK;
      while (lo < hi) { int m = (lo + hi) >> 1; if (bsh[m] < blo) lo = m + 1; else hi = m; }
      qrange[threadIdx.x * 2] = lo >> 6;
      lo = 0; hi = NTOK;
      while (lo < hi) { int m = (lo + hi) >> 1; if (bsh[m] < bhi + 1) lo = m + 1; else hi = m; }
      qrange[threadIdx.x * 2 + 1] = (lo + 63) >> 6;
    }
  }
}

// ---------------- GEMM: C = A(bf16) @ B^T(bf16) + bias -------------------
// 2-buffer, 1-ahead counted-vmcnt pipeline:
//   [barrier -> STAGE(t+1) -> vmcnt(N) -> barrier -> COMPUTE(t)]
// MODE 0: BM=128,BN=64, grid(32,24), 48KB LDS, 3 blocks/CU (no tail: 768=3*256)
// MODE 1: BM=64, BN=64, grid(64,8),  32KB LDS, 2 blocks/CU
template <int MODE>
__global__ __launch_bounds__(256, MODE ? 2 : 3) void gemm_kernel(
    const unsigned short* __restrict__ A,
    const unsigned short* __restrict__ B,
    const float* __restrict__ biasv,
    float* __restrict__ outf,
    unsigned short* __restrict__ qb,
    unsigned short* __restrict__ kb,
    unsigned short* __restrict__ vt) {
  constexpr int BM = MODE ? 64 : 128;
  constexpr int FM = MODE ? 2 : 4;              // m-frags per wave
  constexpr int ALOADS = BM / 32;               // 16B loads/thread for A
  constexpr int BUFBYTES = (BM + 64) * 64 * 2;  // A + B per buffer
  __shared__ __align__(16) unsigned short lds[(BM + 64) * 64 * 2];
  const int tid = threadIdx.x;
  const int lane = tid & 63;
  const int wv = tid >> 6;
  const int wm = wv >> 1, wn = wv & 1;
  const int r16 = lane & 15, g4 = lane >> 4;
  const int mt = blockIdx.x, nt = blockIdx.y;

  f32x4 acc[FM][2];
  #pragma unroll
  for (int i = 0; i < FM; ++i)
    #pragma unroll
    for (int j = 0; j < 2; ++j)
      acc[i][j] = (f32x4){0.f, 0.f, 0.f, 0.f};

  const int srow = tid >> 3;          // 0..31
  const int scolb = (tid & 7) << 4;   // byte col 0..112

#define STAGE(KT, BI)                                                        \
  {                                                                          \
    char* bA = (char*)lds + (BI) * BUFBYTES;                                 \
    char* bB = bA + BM * 128;                                                \
    _Pragma("unroll") for (int i = 0; i < ALOADS; ++i) {                     \
      int row = i * 32 + srow;                                               \
      int cu_ = scolb ^ ((row & 7) << 4);                                    \
      gload_lds16(A + (size_t)(mt * BM + row) * KDIM + (KT) * 64 + (cu_ >> 1), \
                  bA + i * 4096 + wv * 1024);                                \
    }                                                                        \
    _Pragma("unroll") for (int i = 0; i < 2; ++i) {                          \
      int row = i * 32 + srow;                                               \
      int cu_ = scolb ^ ((row & 7) << 4);                                    \
      gload_lds16(B + (size_t)(nt * 64 + row) * KDIM + (KT) * 64 + (cu_ >> 1), \
                  bB + i * 4096 + wv * 1024);                                \
    }                                                                        \
  }

#define COMPUTE(BI)                                                          \
  {                                                                          \
    const char* base = (const char*)lds + (BI) * BUFBYTES;                   \
    _Pragma("unroll") for (int ks = 0; ks < 2; ++ks) {                       \
      bf16x8 af[FM], bfr[2];                                                 \
      _Pragma("unroll") for (int f = 0; f < FM; ++f) {                       \
        int ra = wm * (FM * 16) + f * 16 + r16;                              \
        af[f] = *(const bf16x8*)(base + ra * 128 +                           \
                                 ((ks * 64 + g4 * 16) ^ ((ra & 7) << 4)));   \
      }                                                                      \
      _Pragma("unroll") for (int f = 0; f < 2; ++f) {                        \
        int rb = wn * 32 + f * 16 + r16;                                     \
        bfr[f] = *(const bf16x8*)(base + BM * 128 + rb * 128 +               \
                                  ((ks * 64 + g4 * 16) ^ ((rb & 7) << 4)));  \
      }                                                                      \
      _Pragma("unroll") for (int fm = 0; fm < FM; ++fm)                      \
        _Pragma("unroll") for (int fn = 0; fn < 2; ++fn)                     \
          acc[fm][fn] = mfma16(af[fm], bfr[fn], acc[fm][fn]);                \
    }                                                                        \
  }

  STAGE(0, 0);
  #pragma unroll
  for (int kt = 0; kt < KITER; ++kt) {
    if (kt + 1 < KITER) {
      __builtin_amdgcn_s_barrier();   // WAR: compute(kt-1) done before overwrite
      STAGE(kt + 1, (kt + 1) & 1);
      if constexpr (MODE == 0)
        asm volatile("s_waitcnt vmcnt(6)" ::: "memory");
      else
        asm volatile("s_waitcnt vmcnt(4)" ::: "memory");
    } else {
      asm volatile("s_waitcnt vmcnt(0)" ::: "memory");
    }
    __builtin_amdgcn_s_barrier();     // RAW: all waves' stage(kt) visible
    COMPUTE(kt & 1);
  }
#undef STAGE
#undef COMPUTE

  #pragma unroll
  for (int fm = 0; fm < FM; ++fm) {
    #pragma unroll
    for (int fn = 0; fn < 2; ++fn) {
      int mb = mt * BM + wm * (FM * 16) + fm * 16 + g4 * 4;
      int n = nt * 64 + wn * 32 + fn * 16 + r16;
      float bv = biasv[n];
      if (MODE == 1) {
        #pragma unroll
        for (int r = 0; r < 4; ++r)
          outf[(size_t)(mb + r) * DMODEL + n] = acc[fm][fn][r] + bv;
      } else {
        if (n < 512) {
          #pragma unroll
          for (int r = 0; r < 4; ++r)
            qb[(size_t)(mb + r) * DMODEL + n] = f2bf(acc[fm][fn][r] + bv);
        } else if (n < 1024) {
          int nn = n - 512;
          #pragma unroll
          for (int r = 0; r < 4; ++r)
            kb[(size_t)(mb + r) * DMODEL + nn] = f2bf(acc[fm][fn][r] + bv);
        } else {
          int nn = n - 1024;  // nn = h*64 + d ; vt[nn][m]
          u16x4 pk;
          #pragma unroll
          for (int r = 0; r < 4; ++r) pk[r] = f2bf(acc[fm][fn][r] + bv);
          *(u16x4*)(vt + (size_t)nn * NTOK + mb) = pk;
        }
      }
    }
  }
}

// ---------------- flash attention, batch-block skipping, T14 prefetch ------
// grid 2048 = 256 q-tiles(16 rows) x 8 heads; 1 wave per block.
// blockIdx&7 = head -> round-robin XCD assignment keeps per-head K/V in one L2.
__global__ __launch_bounds__(64) void attn_kernel(
    const unsigned short* __restrict__ qb,
    const unsigned short* __restrict__ kb,
    const unsigned short* __restrict__ vt,
    const float* __restrict__ bias,
    const int* __restrict__ batch,
    const int* __restrict__ qrange,
    unsigned short* __restrict__ ao) {
  __shared__ __align__(16) unsigned short pl[16 * 72];
  const int lane = threadIdx.x & 63;
  const int r16 = lane & 15, g4 = lane >> 4;
  const int h = blockIdx.x & 7;
  const int qt = blockIdx.x >> 3;
  const int qrow0 = qt * 16;
  const int hoff = h * HDIM;

  const unsigned short* qrow = qb + (size_t)(qrow0 + r16) * DMODEL + hoff + g4 * 8;
  bf16x8 qa0 = *(const bf16x8*)qrow;
  bf16x8 qa1 = *(const bf16x8*)(qrow + 32);

  int qbt[4];
  const float* bprow[4];
  const float* bh = bias + (size_t)h * NTOK * NTOK;
  #pragma unroll
  for (int r = 0; r < 4; ++r) {
    qbt[r] = batch[qrow0 + g4 * 4 + r];
    bprow[r] = bh + (size_t)(qrow0 + g4 * 4 + r) * NTOK;
  }

  const int tile0 = qrange[qt * 2];
  const int tile1 = qrange[qt * 2 + 1];

  float m_r[4] = {NEGINF, NEGINF, NEGINF, NEGINF};
  float l_r[4] = {0.f, 0.f, 0.f, 0.f};
  f32x4 o[4];
  #pragma unroll
  for (int d = 0; d < 4; ++d) o[d] = (f32x4){0.f, 0.f, 0.f, 0.f};

#define PREFETCH_KB(T, K0, K1, BV, KBT)                                      \
  {                                                                          \
    int kvb_ = (T) << 6;                                                     \
    _Pragma("unroll") for (int c = 0; c < 4; ++c) {                          \
      const unsigned short* kp =                                             \
          kb + (size_t)(kvb_ + c * 16 + r16) * DMODEL + hoff + g4 * 8;       \
      K0[c] = *(const bf16x8*)kp;                                            \
      K1[c] = *(const bf16x8*)(kp + 32);                                     \
    }                                                                        \
    _Pragma("unroll") for (int c = 0; c < 4; ++c) {                          \
      KBT[c] = batch[kvb_ + c * 16 + r16];                                   \
      _Pragma("unroll") for (int r = 0; r < 4; ++r)                          \
        BV[c][r] = bprow[r][kvb_ + c * 16 + r16];                            \
    }                                                                        \
  }

#define TILE_STEP(T, K0C, K1C, BVC, KBTC, K0N, K1N, BVN, KBTN)               \
  {                                                                          \
    int kvb = (T) << 6;                                                      \
    f32x4 s[4];                                                              \
    __builtin_amdgcn_s_setprio(1);                                           \
    _Pragma("unroll") for (int c = 0; c < 4; ++c) {                          \
      f32x4 z = (f32x4){0.f, 0.f, 0.f, 0.f};                                 \
      z = mfma16(qa0, K0C[c], z);                                            \
      z = mfma16(qa1, K1C[c], z);                                            \
      s[c] = z;                                                              \
    }                                                                        \
    __builtin_amdgcn_s_setprio(0);                                           \
    /* V loads for current tile (L2-resident: issued ~600cy before PV) */    \
    bf16x8 v0[4], v1[4];                                                     \
    _Pragma("unroll") for (int d = 0; d < 4; ++d) {                          \
      const unsigned short* vp =                                             \
          vt + (size_t)(hoff + d * 16 + r16) * NTOK + kvb + g4 * 8;          \
      v0[d] = *(const bf16x8*)vp;                                            \
      v1[d] = *(const bf16x8*)(vp + 32);                                     \
    }                                                                        \
    /* issue next tile's K + bias + tags (HBM latency hides under compute)*/ \
    {                                                                        \
      int tn_ = ((T) + 1 < tile1) ? (T) + 1 : (T);                           \
      PREFETCH_KB(tn_, K0N, K1N, BVN, KBTN);                                 \
    }                                                                        \
    _Pragma("unroll") for (int c = 0; c < 4; ++c)                            \
      _Pragma("unroll") for (int r = 0; r < 4; ++r)                          \
        s[c][r] = (qbt[r] == KBTC[c]) ? (s[c][r] + BVC[c][r]) : NEGINF;      \
    float scl[4];                                                            \
    _Pragma("unroll") for (int r = 0; r < 4; ++r) {                          \
      float tm = fmaxf(fmaxf(s[0][r], s[1][r]), fmaxf(s[2][r], s[3][r]));    \
      tm = fmaxf(tm, __shfl_xor(tm, 1));                                     \
      tm = fmaxf(tm, __shfl_xor(tm, 2));                                     \
      tm = fmaxf(tm, __shfl_xor(tm, 4));                                     \
      tm = fmaxf(tm, __shfl_xor(tm, 8));                                     \
      float mn = fmaxf(m_r[r], tm);                                          \
      bool dead = (mn == NEGINF);                                            \
      scl[r] = dead ? 1.0f : __expf(m_r[r] - mn);                            \
      m_r[r] = mn;                                                           \
      float rs = 0.f;                                                        \
      _Pragma("unroll") for (int c = 0; c < 4; ++c) {                        \
        float p = dead ? 0.0f : __expf(s[c][r] - mn);                        \
        s[c][r] = p;                                                         \
        rs += p;                                                             \
      }                                                                      \
      rs += __shfl_xor(rs, 1);                                               \
      rs += __shfl_xor(rs, 2);                                               \
      rs += __shfl_xor(rs, 4);                                               \
      rs += __shfl_xor(rs, 8);                                               \
      l_r[r] = l_r[r] * scl[r] + rs;                                         \
    }                                                                        \
    _Pragma("unroll") for (int c = 0; c < 4; ++c)                            \
      _Pragma("unroll") for (int r = 0; r < 4; ++r)                          \
        pl[(g4 * 4 + r) * 72 + c * 16 + r16] = f2bf(s[c][r]);                \
    asm volatile("" ::: "memory");                                           \
    u16x8 pr0 = *(const u16x8*)(pl + r16 * 72 + g4 * 8);                     \
    u16x8 pr1 = *(const u16x8*)(pl + r16 * 72 + 32 + g4 * 8);                \
    bf16x8 pa0 = __builtin_bit_cast(bf16x8, pr0);                            \
    bf16x8 pa1 = __builtin_bit_cast(bf16x8, pr1);                            \
    _Pragma("unroll") for (int d = 0; d < 4; ++d) {                          \
      _Pragma("unroll") for (int r = 0; r < 4; ++r) o[d][r] *= scl[r];       \
    }                                                                        \
    __builtin_amdgcn_s_setprio(1);                                           \
    _Pragma("unroll") for (int d = 0; d < 4; ++d) {                          \
      o[d] = mfma16(pa0, v0[d], o[d]);                                       \
      o[d] = mfma16(pa1, v1[d], o[d]);                                       \
    }                                                                        \
    __builtin_amdgcn_s_setprio(0);                                           \
  }

  // ping-pong prefetch register sets (no runtime-indexed arrays: rule #20)
  bf16x8 ka0[4], ka1[4], kc0[4], kc1[4];
  float bva[4][4], bvb[4][4];
  int kta[4], ktb[4];
  PREFETCH_KB(tile0, ka0, ka1, bva, kta);
  int t = tile0;
  while (true) {
    TILE_STEP(t, ka0, ka1, bva, kta, kc0, kc1, bvb, ktb);
    if (++t >= tile1) break;
    TILE_STEP(t, kc0, kc1, bvb, ktb, ka0, ka1, bva, kta);
    if (++t >= tile1) break;
  }

  // normalize + store
  #pragma unroll
  for (int r = 0; r < 4; ++r) {
    float inv = (l_r[r] > 0.f) ? 1.0f / l_r[r] : 0.0f;
    #pragma unroll
    for (int d = 0; d < 4; ++d)
      ao[(size_t)(qrow0 + g4 * 4 + r) * DMODEL + hoff + d * 16 + r16] =
          f2bf(o[d][r] * inv);
  }
#undef PREFETCH_KB
#undef TILE_STEP
}

// ---------------------------------------------------------------------------
extern "C" void kernel_launch(void* const* d_in, const int* in_sizes, int n_in,
                              void* d_out, int out_size, void* d_ws, size_t ws_size,
                              hipStream_t stream) {
  const float* x  = (const float*)d_in[0];
  const float* ab = (const float*)d_in[1];
  const int* batch = (const int*)d_in[2];
  const float* Wq = (const float*)d_in[3];
  const float* bq = (const float*)d_in[4];
  const float* Wk = (const float*)d_in[5];
  const float* bk = (const float*)d_in[6];
  const float* Wv = (const float*)d_in[7];
  const float* bv = (const float*)d_in[8];
  const float* Wo = (const float*)d_in[9];
  const float* bo = (const float*)d_in[10];
  float* out = (float*)d_out;

  char* ws = (char*)d_ws;
  const size_t MB = 1024 * 1024;
  unsigned short* xb   = (unsigned short*)(ws);            // 4 MB
  unsigned short* qb   = (unsigned short*)(ws + 4 * MB);   // 4 MB
  unsigned short* kb   = (unsigned short*)(ws + 8 * MB);   // 4 MB
  unsigned short* vt   = (unsigned short*)(ws + 12 * MB);  // 4 MB  [h*64+d][n]
  unsigned short* aout = (unsigned short*)(ws + 16 * MB);  // 4 MB
  unsigned short* wqkv = (unsigned short*)(ws + 20 * MB);  // 1.5 MB
  unsigned short* wo   = (unsigned short*)(ws + 22 * MB);  // 0.5 MB
  float* bqkv          = (float*)(ws + 23 * MB);           // 6 KB
  int* qrange          = (int*)(ws + 23 * MB + 65536);     // 2 KB

  convert_kernel<<<dim3(1024), dim3(256), 0, stream>>>(
      x, Wq, bq, Wk, bk, Wv, bv, Wo, batch, xb, wqkv, wo, bqkv, qrange);

  gemm_kernel<0><<<dim3(32, 24), dim3(256), 0, stream>>>(
      xb, wqkv, bqkv, nullptr, qb, kb, vt);

  attn_kernel<<<dim3(2048), dim3(64), 0, stream>>>(
      qb, kb, vt, ab, batch, qrange, aout);

  gemm_kernel<1><<<dim3(64, 8), dim3(256), 0, stream>>>(
      aout, wo, bo, out, nullptr, nullptr, nullptr);
}